// Round 2
// baseline (352.863 us; speedup 1.0000x reference)
//
#include <hip/hip_runtime.h>
#include <hip/hip_bf16.h>
#include <math.h>
#include <stdint.h>

#define BATCH 2
#define SEQ   2048
#define DMODEL 1024
#define NHEAD 16
#define HDIM  64
#define NROWS (BATCH*SEQ)          // 4096
#define EPS   1e-6f
#define QSCALE 0.1803368801111204f // 0.125 * log2(e): softmax in exp2 domain

typedef float f32x4 __attribute__((ext_vector_type(4)));
typedef short s16x8 __attribute__((ext_vector_type(8)));

// ws layout (ushort units):
//  xq @ 0            (4194304)   -> reused as ab (attention out) after projections
//  xk @ 4194304
//  xv @ 8388608
//  wq @ 12582912     (1048576 each)
//  wk @ 13631488
//  wv @ 14680064
//  wo @ 15728640
//  qb @ 16777216     [B,H,S,64] bf16, pre-scaled by QSCALE
//  kb @ 20971520     [B,H,S,64] bf16
//  vt @ 25165824     [B,H,64,S] bf16 (V transposed)
//  cmask @ 29360128  (1 MB): [B][32 kblocks][S] uint64 bitmask
//  msum  @ 29884416  (128 B): [B][16 qb128] uint32, bit kb = "has masked"
#define OFF_XQ 0
#define OFF_XK 4194304
#define OFF_XV 8388608
#define OFF_WQ 12582912
#define OFF_WK 13631488
#define OFF_WV 14680064
#define OFF_WO 15728640
#define OFF_QB 16777216
#define OFF_KB 20971520
#define OFF_VT 25165824
#define OFF_CM 29360128
#define OFF_MS 29884416

__device__ __forceinline__ unsigned short f2bf(float x) {
    unsigned int u = __builtin_bit_cast(unsigned int, x);
    u += 0x7fff + ((u >> 16) & 1);            // round-to-nearest-even
    return (unsigned short)(u >> 16);
}

__device__ __forceinline__ void gl_lds16(const void* g, void* l) {
    __builtin_amdgcn_global_load_lds(
        (const __attribute__((address_space(1))) unsigned int*)g,
        (__attribute__((address_space(3))) unsigned int*)(unsigned int)(unsigned long long)l,
        16, 0, 0);
}

// ---------------------------------------------------------------------------
// fused fp32 -> bf16 convert of query/key/value + 4 weight matrices
// (also zero-inits the mask summary words for the following dispatch)
// ---------------------------------------------------------------------------
__global__ __launch_bounds__(256) void conv_all_kernel(
    const float* __restrict__ q, const float* __restrict__ k, const float* __restrict__ v,
    const float* __restrict__ wq, const float* __restrict__ wk, const float* __restrict__ wv,
    const float* __restrict__ wo, unsigned short* __restrict__ ws)
{
    if (blockIdx.x == 0 && threadIdx.x < 32)
        ((unsigned int*)(ws + OFF_MS))[threadIdx.x] = 0;
    size_t t = ((size_t)blockIdx.x * 256 + threadIdx.x) * 4;
    const float* src; unsigned short* dst; size_t off;
    if (t < 4194304)       { src = q;  dst = ws + OFF_XQ; off = t; }
    else if (t < 8388608)  { src = k;  dst = ws + OFF_XK; off = t - 4194304; }
    else if (t < 12582912) { src = v;  dst = ws + OFF_XV; off = t - 8388608; }
    else if (t < 13631488) { src = wq; dst = ws + OFF_WQ; off = t - 12582912; }
    else if (t < 14680064) { src = wk; dst = ws + OFF_WK; off = t - 13631488; }
    else if (t < 15728640) { src = wv; dst = ws + OFF_WV; off = t - 14680064; }
    else                   { src = wo; dst = ws + OFF_WO; off = t - 15728640; }
    float4 x = *(const float4*)&src[off];
    ushort4 o;
    o.x = f2bf(x.x); o.y = f2bf(x.y); o.z = f2bf(x.z); o.w = f2bf(x.w);
    *(ushort4*)&dst[off] = o;
}

// ---------------------------------------------------------------------------
// mask -> per-(b, kblock, s) 64-bit bitmask + per-(b, qb128) chunk summary
// ---------------------------------------------------------------------------
__global__ __launch_bounds__(256) void mask_compress_kernel(
    const int* __restrict__ mask, unsigned long long* __restrict__ cm,
    unsigned int* __restrict__ msum)
{
    int t = blockIdx.x * 256 + threadIdx.x;  // [0, 2*32*2048)
    int s  = t & 2047;
    int kb = (t >> 11) & 31;
    int b  = t >> 16;
    const int* mp = mask + ((size_t)b * SEQ + s) * SEQ + kb * 64;
    unsigned long long bits = 0;
    #pragma unroll
    for (int i = 0; i < 16; i++) {
        int4 m4 = *(const int4*)&mp[i * 4];
        unsigned long long nib =
            (unsigned long long)((m4.x != 0) | ((m4.y != 0) << 1) |
                                 ((m4.z != 0) << 2) | ((m4.w != 0) << 3));
        bits |= nib << (i * 4);
    }
    cm[((size_t)b * 32 + kb) * SEQ + s] = bits;
    if (bits != ~0ull)
        atomicOr(&msum[(b << 4) | (s >> 7)], 1u << kb);
}

// ---------------------------------------------------------------------------
// Shared GEMM tile body: C[128x128] += A[r0..] * W[c0..]^T, bf16 MFMA.
// A,W row-major bf16 with K stride 1024. Per-wave 64x64 = 4x4 C-frags.
// LDS rows (128 B) are XOR-ROTATED by row index: phys 16B-group p of row r
// holds logical group (p - r) & 7 (rotation folded into the GLOBAL source
// address, since global_load_lds's LDS side is fixed base + lane*16).
// Fragment reads use group ((ks*4+quad) + row) & 7 -> consecutive rows hit
// rotated bank groups (2-way aliasing = free) instead of 16 rows on one
// bank group (the 9.4e6-conflict hotspot measured in R8).
// ---------------------------------------------------------------------------
__device__ __forceinline__ void gemm_body(
    const unsigned short* A, const unsigned short* W, int r0, int c0,
    unsigned short* As, unsigned short* Bs, f32x4 acc[4][4])
{
    const int tid  = threadIdx.x;
    const int wave = tid >> 6, lane = tid & 63;
    const int quad = lane >> 4, l15 = lane & 15;
    const int wr = wave >> 1, wc = wave & 1;
    for (int k0 = 0; k0 < DMODEL; k0 += 64) {
        __syncthreads();
        #pragma unroll
        for (int r = 0; r < 4; r++) {
            int f   = r * 4096 + tid * 16;    // byte offset in 16KB tile
            int row = f >> 7;                 // tile row 0..127
            int g   = (((f >> 4) & 7) - row) & 7;   // logical group at this slot
            gl_lds16((const char*)A + (size_t)(r0 + row) * 2048 + k0 * 2 + g * 16,
                     (char*)As + r * 4096 + wave * 1024);
            gl_lds16((const char*)W + (size_t)(c0 + row) * 2048 + k0 * 2 + g * 16,
                     (char*)Bs + r * 4096 + wave * 1024);
        }
        __syncthreads();
        #pragma unroll
        for (int ks = 0; ks < 2; ks++) {
            s16x8 a[4], b[4];
            #pragma unroll
            for (int mt = 0; mt < 4; mt++) {
                int row = wr*64 + mt*16 + l15;
                a[mt] = *(const s16x8*)((const char*)As + row * 128 + ((ks*4 + quad + row) & 7) * 16);
            }
            #pragma unroll
            for (int nt = 0; nt < 4; nt++) {
                int row = wc*64 + nt*16 + l15;
                b[nt] = *(const s16x8*)((const char*)Bs + row * 128 + ((ks*4 + quad + row) & 7) * 16);
            }
            #pragma unroll
            for (int mt = 0; mt < 4; mt++)
                #pragma unroll
                for (int nt = 0; nt < 4; nt++)
                    acc[mt][nt] = __builtin_amdgcn_mfma_f32_16x16x32_bf16(a[mt], b[nt], acc[mt][nt], 0, 0, 0);
        }
    }
}

// ---------------------------------------------------------------------------
// QKV projections: z=0 -> q (scaled, [B,H,S,d]), z=1 -> k ([B,H,S,d]),
// z=2 -> V^T computed DIRECTLY as Wv * X^T (operand swap, coalesced stores).
// ---------------------------------------------------------------------------
__global__ __launch_bounds__(256) void qkv_gemm_kernel(
    unsigned short* __restrict__ ws,
    const float* __restrict__ bq, const float* __restrict__ bk, const float* __restrict__ bv)
{
    __shared__ __align__(16) unsigned short As[8192];
    __shared__ __align__(16) unsigned short Bs[8192];
    const int z = blockIdx.z;
    const unsigned short *A, *W;
    int r0, c0;
    if (z != 2) {
        A = ws + (size_t)z * 4194304;            // xq/xk
        W = ws + OFF_WQ + (size_t)z * 1048576;
        r0 = blockIdx.x * 128; c0 = blockIdx.y * 128;
    } else {
        A = ws + OFF_WV;                         // rows = output features
        W = ws + OFF_XV;                         // "cols" = seq rows
        r0 = blockIdx.y * 128; c0 = blockIdx.x * 128;
    }
    const float* bias = (z == 0) ? bq : (z == 1 ? bk : bv);
    unsigned short* outp = ws + OFF_QB + (size_t)z * 4194304;      // qb/kb/vt
    const float scale = (z == 0) ? QSCALE : 1.0f;

    f32x4 acc[4][4] = {};
    gemm_body(A, W, r0, c0, As, Bs, acc);

    const int lane = threadIdx.x & 63, wave = threadIdx.x >> 6;
    const int quad = lane >> 4, l15 = lane & 15;
    const int wr = wave >> 1, wc = wave & 1;
    if (z != 2) {
        float bias_v[4];
        #pragma unroll
        for (int nt = 0; nt < 4; nt++) bias_v[nt] = bias[c0 + wc*64 + nt*16 + l15];
        #pragma unroll
        for (int mt = 0; mt < 4; mt++) {
            #pragma unroll
            for (int nt = 0; nt < 4; nt++) {
                int c = c0 + wc*64 + nt*16 + l15;
                int hh = c >> 6, dd = c & 63;
                #pragma unroll
                for (int reg = 0; reg < 4; reg++) {
                    int r = r0 + wr*64 + mt*16 + quad*4 + reg;
                    int bb = r >> 11, ss = r & (SEQ - 1);
                    float val = (acc[mt][nt][reg] + bias_v[nt]) * scale;
                    outp[(((size_t)(bb*NHEAD + hh)) * SEQ + ss) * HDIM + dd] = f2bf(val);
                }
            }
        }
    } else {
        #pragma unroll
        for (int mt = 0; mt < 4; mt++) {
            #pragma unroll
            for (int reg = 0; reg < 4; reg++) {
                int f = r0 + wr*64 + mt*16 + quad*4 + reg;   // feature
                int hh = f >> 6, dd = f & 63;
                float bfv = bias[f];
                #pragma unroll
                for (int nt = 0; nt < 4; nt++) {
                    int r = c0 + wc*64 + nt*16 + l15;        // seq row
                    int bb = r >> 11, ss = r & (SEQ - 1);
                    outp[(((size_t)(bb*NHEAD + hh)) * HDIM + dd) * SEQ + ss] =
                        f2bf(acc[mt][nt][reg] + bfv);
                }
            }
        }
    }
}

// ---------------------------------------------------------------------------
// Out projection: out = ab @ Wo^T + bo + residual  (fp32 out)
// ---------------------------------------------------------------------------
__global__ __launch_bounds__(256) void oproj_gemm_kernel(
    const unsigned short* __restrict__ ws, const float* __restrict__ bo,
    const float* __restrict__ resid, float* __restrict__ outf)
{
    __shared__ __align__(16) unsigned short As[8192];
    __shared__ __align__(16) unsigned short Bs[8192];
    const unsigned short* A = ws + OFF_XQ;      // ab lives where xq was
    const unsigned short* W = ws + OFF_WO;
    const int r0 = blockIdx.x * 128, c0 = blockIdx.y * 128;

    f32x4 acc[4][4] = {};
    gemm_body(A, W, r0, c0, (unsigned short*)As, (unsigned short*)Bs, acc);

    const int lane = threadIdx.x & 63, wave = threadIdx.x >> 6;
    const int quad = lane >> 4, l15 = lane & 15;
    const int wr = wave >> 1, wc = wave & 1;
    #pragma unroll
    for (int mt = 0; mt < 4; mt++) {
        #pragma unroll
        for (int nt = 0; nt < 4; nt++) {
            int c = c0 + wc*64 + nt*16 + l15;
            float bv = bo[c];
            #pragma unroll
            for (int reg = 0; reg < 4; reg++) {
                int r = r0 + wr*64 + mt*16 + quad*4 + reg;
                size_t idx = (size_t)r * DMODEL + c;
                outf[idx] = acc[mt][nt][reg] + bv + resid[idx];
            }
        }
    }
}

// ---------------------------------------------------------------------------
// Flash attention, bf16 MFMA, static softmax.
// R10: back to the R5 shape (512 thr, 8 waves x 16 q-rows, 2 blocks/CU =
// 16 waves/CU -- R9 showed 8 waves/CU cannot hide the barrier drain), but
// K moved from LDS to REGISTERS: the K-fragment B-operand layout
// K[key=nt*16+l15][ks*32+quad*8..+7] is directly loadable from global
// (16 rows x 64B segments, L1-shared across the block's 8 waves).
// This removes 8 ds_read_b128/chunk/wave (LDS port model: 325 -> ~221
// cy/wave-chunk; R5 was port-saturated at 166K cy/CU vs 157K available)
// and halves the DMA drained at each barrier. Next chunk's K loads issue
// right after QK^T consumes the current ones (WAR keeps order; mask/exp2/
// P/PV ~400cy hides L2 latency). V^T stays LDS-staged (global_load_lds,
// XOR-rotated rows, double-buffered); l via MFMA ones-column; P packed by
// truncation (bias cancels in P/l); per-(b,qb128) chunk summary skips
// mask loads when all-ones.
// ---------------------------------------------------------------------------
__global__ __launch_bounds__(512, 4) void attn_mfma_kernel(
    const unsigned short* __restrict__ ws,
    const unsigned long long* __restrict__ cmask,
    const unsigned int* __restrict__ msum,
    unsigned short* __restrict__ ab)
{
    const int tid  = threadIdx.x;
    const int wave = tid >> 6, lane = tid & 63;
    const int quad = lane >> 4, l15 = lane & 15;
    const int h = blockIdx.y, b = blockIdx.z;
    const int qw = blockIdx.x * 128 + wave * 16;

    const char* qh = (const char*)(ws + OFF_QB + ((size_t)(b*NHEAD + h)) * SEQ * HDIM);
    const char* kh = (const char*)(ws + OFF_KB + ((size_t)(b*NHEAD + h)) * SEQ * HDIM);
    const char* vh = (const char*)(ws + OFF_VT + ((size_t)(b*NHEAD + h)) * SEQ * HDIM);

    __shared__ __align__(16) char Vs[2][8192];   // [d][key] rows, groups rotated
    __shared__ __align__(16) unsigned short Pl[8][16 * 72];
    unsigned short* Pw = Pl[wave];

    const unsigned int chunkflags = msum[(b << 4) | blockIdx.x];

    // V staging: 512 threads x 16B = one 8KB buffer per call; row = tid>>3,
    // phys group tid&7 holds logical group ((tid&7) - row) & 7 (XOR-rotate)
    const int srow = tid >> 3;
    const int sgrp = ((tid & 7) - srow) & 7;

    #define STAGEV(bfi, k0)                                                     \
        gl_lds16(vh + (size_t)srow * 4096 + (size_t)(k0) * 2 + sgrp * 16,       \
                 Vs[bfi] + wave * 1024)

    s16x8 qa[2];
    #pragma unroll
    for (int ks = 0; ks < 2; ks++)
        qa[ks] = *(const s16x8*)(qh + (size_t)(qw + l15) * 128 + ks*64 + quad*16);

    s16x8 onesf;
    {
        short so = (short)0x3F80;  // bf16 1.0
        if (l15 == 0) onesf = (s16x8){so, so, so, so, so, so, so, so};
        else          onesf = (s16x8){0, 0, 0, 0, 0, 0, 0, 0};
    }

    f32x4 o[4], lsum = {0.f, 0.f, 0.f, 0.f};
    #pragma unroll
    for (int nt = 0; nt < 4; nt++) o[nt] = (f32x4){0.f, 0.f, 0.f, 0.f};

    // K fragments for chunk 0, loaded straight to registers in B-operand
    // layout: kreg[nt][ks] = K[k0 + nt*16 + l15][ks*32 + quad*8 .. +7]
    s16x8 kreg[4][2];
    #pragma unroll
    for (int nt = 0; nt < 4; nt++)
        #pragma unroll
        for (int ks = 0; ks < 2; ks++)
            kreg[nt][ks] = *(const s16x8*)(kh + (size_t)(nt*16 + l15) * 128 + ks*64 + quad*16);

    STAGEV(0, 0);
    int bf = 0;
    for (int k0 = 0; k0 < SEQ; k0 += 64) {
        __syncthreads();            // vmcnt(0): V buf[bf] staged, buf[bf^1] free
        if (k0 + 64 < SEQ) STAGEV(bf ^ 1, k0 + 64);

        const char* Vb = Vs[bf];
        // --- S = Q K^T (exp2-domain, pre-scaled), K from registers ---
        f32x4 s[4];
        #pragma unroll
        for (int nt = 0; nt < 4; nt++) {
            f32x4 z = {0.f, 0.f, 0.f, 0.f};
            s[nt] = __builtin_amdgcn_mfma_f32_16x16x32_bf16(qa[0], kreg[nt][0], z, 0, 0, 0);
            s[nt] = __builtin_amdgcn_mfma_f32_16x16x32_bf16(qa[1], kreg[nt][1], s[nt], 0, 0, 0);
        }
        // --- prefetch next chunk's K into the same regs (WAR keeps order;
        //     in flight during mask/exp2/P/PV, consumed after next barrier) ---
        if (k0 + 64 < SEQ) {
            #pragma unroll
            for (int nt = 0; nt < 4; nt++)
                #pragma unroll
                for (int ks = 0; ks < 2; ks++)
                    kreg[nt][ks] = *(const s16x8*)(kh +
                        (size_t)(k0 + 64 + nt*16 + l15) * 128 + ks*64 + quad*16);
        }
        // --- mask (wave-uniform skip when this chunk is all-ones) ---
        if (chunkflags & (1u << (k0 >> 6))) {
            const unsigned long long* cmp =
                cmask + ((size_t)b*32 + (k0 >> 6)) * SEQ + qw + quad*4;
            #pragma unroll
            for (int reg = 0; reg < 4; reg++) {
                unsigned long long cm = cmp[reg];
                if (cm != ~0ull) {
                    #pragma unroll
                    for (int nt = 0; nt < 4; nt++) {
                        int n = nt*16 + l15;
                        if (!((cm >> n) & 1)) s[nt][reg] = -1e9f;
                    }
                }
            }
        }
        // --- P = exp2(S) -> LDS (bf16 trunc; bias cancels in P/l) ---
        #pragma unroll
        for (int nt = 0; nt < 4; nt++)
            #pragma unroll
            for (int reg = 0; reg < 4; reg++) {
                float pv = exp2f(s[nt][reg]);
                Pw[(quad*4 + reg) * 72 + nt*16 + l15] =
                    (unsigned short)(__builtin_bit_cast(unsigned int, pv) >> 16);
            }
        // --- O += P @ V ; l += P @ 1 (ones-column MFMA) ---
        #pragma unroll
        for (int ks = 0; ks < 2; ks++) {
            s16x8 pa = *(const s16x8*)((const char*)Pw + l15 * 144 + ks*64 + quad*16);
            lsum = __builtin_amdgcn_mfma_f32_16x16x32_bf16(pa, onesf, lsum, 0, 0, 0);
            #pragma unroll
            for (int nt = 0; nt < 4; nt++) {
                int d = nt*16 + l15;
                s16x8 vf = *(const s16x8*)(Vb + d*128 + ((ks*4 + quad + d) & 7) * 16);
                o[nt] = __builtin_amdgcn_mfma_f32_16x16x32_bf16(pa, vf, o[nt], 0, 0, 0);
            }
        }
        bf ^= 1;
    }
    #undef STAGEV
    // --- epilogue: O / l -> ab [B,S,DMODEL] bf16 (l at lanes l15==0) ---
    #pragma unroll
    for (int reg = 0; reg < 4; reg++) {
        float lv = __shfl(lsum[reg], lane & 48);
        float inv = 1.f / lv;
        int sg = qw + quad*4 + reg;
        #pragma unroll
        for (int nt = 0; nt < 4; nt++) {
            size_t idx = ((size_t)b * SEQ + sg) * DMODEL + h*HDIM + nt*16 + l15;
            ab[idx] = f2bf(o[nt][reg] * inv);
        }
    }
}

// ---------------------------------------------------------------------------
// LayerNorm (unbiased std, (std+eps) denominator), in-place on fp32 rows
// ---------------------------------------------------------------------------
__global__ __launch_bounds__(256) void ln_kernel(
    float* __restrict__ x, const float* __restrict__ gamma,
    const float* __restrict__ beta)
{
    const int row = blockIdx.x;
    const int tid = threadIdx.x;
    float4 vals = *(const float4*)&x[(size_t)row * DMODEL + tid * 4];
    float s  = vals.x + vals.y + vals.z + vals.w;
    float ss = vals.x*vals.x + vals.y*vals.y + vals.z*vals.z + vals.w*vals.w;
    #pragma unroll
    for (int off = 32; off > 0; off >>= 1) {
        s  += __shfl_down(s, off);
        ss += __shfl_down(ss, off);
    }
    __shared__ float sbuf[4], ssbuf[4];
    __shared__ float mean_s, inv_s;
    if ((tid & 63) == 0) { sbuf[tid >> 6] = s; ssbuf[tid >> 6] = ss; }
    __syncthreads();
    if (tid == 0) {
        float S1 = 0.f, S2 = 0.f;
        #pragma unroll
        for (int i = 0; i < 4; i++) { S1 += sbuf[i]; S2 += ssbuf[i]; }
        float mean = S1 * (1.0f / DMODEL);
        float var  = (S2 - (float)DMODEL * mean * mean) * (1.0f / (DMODEL - 1));
        float sd   = sqrtf(fmaxf(var, 0.f));
        mean_s = mean;
        inv_s  = 1.f / (sd + EPS);
    }
    __syncthreads();
    float4 g  = *(const float4*)&gamma[tid * 4];
    float4 bt = *(const float4*)&beta[tid * 4];
    float4 o;
    o.x = g.x * (vals.x - mean_s) * inv_s + bt.x;
    o.y = g.y * (vals.y - mean_s) * inv_s + bt.y;
    o.z = g.z * (vals.z - mean_s) * inv_s + bt.z;
    o.w = g.w * (vals.w - mean_s) * inv_s + bt.w;
    *(float4*)&x[(size_t)row * DMODEL + tid * 4] = o;
}

extern "C" void kernel_launch(void* const* d_in, const int* in_sizes, int n_in,
                              void* d_out, int out_size, void* d_ws, size_t ws_size,
                              hipStream_t stream) {
    const float* query = (const float*)d_in[0];
    const float* key   = (const float*)d_in[1];
    const float* value = (const float*)d_in[2];
    const int*   mask  = (const int*)d_in[3];
    const float* Wq = (const float*)d_in[4];  const float* bq = (const float*)d_in[5];
    const float* Wk = (const float*)d_in[6];  const float* bk = (const float*)d_in[7];
    const float* Wv = (const float*)d_in[8];  const float* bv = (const float*)d_in[9];
    const float* Wo = (const float*)d_in[10]; const float* bo = (const float*)d_in[11];
    const float* gamma = (const float*)d_in[12];
    const float* beta  = (const float*)d_in[13];
    float* out = (float*)d_out;

    unsigned short* ws = (unsigned short*)d_ws;
    unsigned long long* cmask = (unsigned long long*)(ws + OFF_CM);
    unsigned int* msum = (unsigned int*)(ws + OFF_MS);

    conv_all_kernel<<<16384, 256, 0, stream>>>(query, key, value, Wq, Wk, Wv, Wo, ws);
    mask_compress_kernel<<<512, 256, 0, stream>>>(mask, cmask, msum);
    qkv_gemm_kernel<<<dim3(32, 8, 3), 256, 0, stream>>>(ws, bq, bk, bv);
    attn_mfma_kernel<<<dim3(SEQ/128, NHEAD, BATCH), 512, 0, stream>>>(ws, cmask, msum, ws + OFF_XQ);
    oproj_gemm_kernel<<<dim3(32, 8), 256, 0, stream>>>(ws, bo, query, out);
    ln_kernel<<<NROWS, 256, 0, stream>>>(out, gamma, beta);
}

// Round 3
// 287.118 us; speedup vs baseline: 1.2290x; 1.2290x over previous
//
#include <hip/hip_runtime.h>
#include <hip/hip_bf16.h>
#include <math.h>
#include <stdint.h>

#define BATCH 2
#define SEQ   2048
#define DMODEL 1024
#define NHEAD 16
#define HDIM  64
#define NROWS (BATCH*SEQ)          // 4096
#define EPS   1e-6f
#define QSCALE 0.1803368801111204f // 0.125 * log2(e): softmax in exp2 domain

typedef float f32x4 __attribute__((ext_vector_type(4)));
typedef short s16x8 __attribute__((ext_vector_type(8)));

// ws layout (ushort units):
//  xq @ 0            (4194304)   -> reused as ab (attention out) after projections
//  xk @ 4194304
//  xv @ 8388608
//  wq @ 12582912     (1048576 each)
//  wk @ 13631488
//  wv @ 14680064
//  wo @ 15728640
//  qb @ 16777216     [B,H,S,64] bf16, pre-scaled by QSCALE
//  kb @ 20971520     [B,H,S,64] bf16
//  vt @ 25165824     [B,H,64,S] bf16 (V transposed)
//  cmask @ 29360128  (1 MB): [B][32 kblocks][S] uint64 bitmask
//  msum  @ 29884416  (128 B): [B][16 qb128] uint32, bit kb = "has masked"
#define OFF_XQ 0
#define OFF_XK 4194304
#define OFF_XV 8388608
#define OFF_WQ 12582912
#define OFF_WK 13631488
#define OFF_WV 14680064
#define OFF_WO 15728640
#define OFF_QB 16777216
#define OFF_KB 20971520
#define OFF_VT 25165824
#define OFF_CM 29360128
#define OFF_MS 29884416

__device__ __forceinline__ unsigned short f2bf(float x) {
    unsigned int u = __builtin_bit_cast(unsigned int, x);
    u += 0x7fff + ((u >> 16) & 1);            // round-to-nearest-even
    return (unsigned short)(u >> 16);
}

__device__ __forceinline__ void gl_lds16(const void* g, void* l) {
    __builtin_amdgcn_global_load_lds(
        (const __attribute__((address_space(1))) unsigned int*)g,
        (__attribute__((address_space(3))) unsigned int*)(unsigned int)(unsigned long long)l,
        16, 0, 0);
}

// ---------------------------------------------------------------------------
// fused fp32 -> bf16 convert of query/key/value + 4 weight matrices
// (also zero-inits the mask summary words for the following dispatch)
// ---------------------------------------------------------------------------
__global__ __launch_bounds__(256) void conv_all_kernel(
    const float* __restrict__ q, const float* __restrict__ k, const float* __restrict__ v,
    const float* __restrict__ wq, const float* __restrict__ wk, const float* __restrict__ wv,
    const float* __restrict__ wo, unsigned short* __restrict__ ws)
{
    if (blockIdx.x == 0 && threadIdx.x < 32)
        ((unsigned int*)(ws + OFF_MS))[threadIdx.x] = 0;
    size_t t = ((size_t)blockIdx.x * 256 + threadIdx.x) * 4;
    const float* src; unsigned short* dst; size_t off;
    if (t < 4194304)       { src = q;  dst = ws + OFF_XQ; off = t; }
    else if (t < 8388608)  { src = k;  dst = ws + OFF_XK; off = t - 4194304; }
    else if (t < 12582912) { src = v;  dst = ws + OFF_XV; off = t - 8388608; }
    else if (t < 13631488) { src = wq; dst = ws + OFF_WQ; off = t - 12582912; }
    else if (t < 14680064) { src = wk; dst = ws + OFF_WK; off = t - 13631488; }
    else if (t < 15728640) { src = wv; dst = ws + OFF_WV; off = t - 14680064; }
    else                   { src = wo; dst = ws + OFF_WO; off = t - 15728640; }
    float4 x = *(const float4*)&src[off];
    ushort4 o;
    o.x = f2bf(x.x); o.y = f2bf(x.y); o.z = f2bf(x.z); o.w = f2bf(x.w);
    *(ushort4*)&dst[off] = o;
}

// ---------------------------------------------------------------------------
// mask -> per-(b, kblock, s) 64-bit bitmask + per-(b, qb128) chunk summary
// ---------------------------------------------------------------------------
__global__ __launch_bounds__(256) void mask_compress_kernel(
    const int* __restrict__ mask, unsigned long long* __restrict__ cm,
    unsigned int* __restrict__ msum)
{
    int t = blockIdx.x * 256 + threadIdx.x;  // [0, 2*32*2048)
    int s  = t & 2047;
    int kb = (t >> 11) & 31;
    int b  = t >> 16;
    const int* mp = mask + ((size_t)b * SEQ + s) * SEQ + kb * 64;
    unsigned long long bits = 0;
    #pragma unroll
    for (int i = 0; i < 16; i++) {
        int4 m4 = *(const int4*)&mp[i * 4];
        unsigned long long nib =
            (unsigned long long)((m4.x != 0) | ((m4.y != 0) << 1) |
                                 ((m4.z != 0) << 2) | ((m4.w != 0) << 3));
        bits |= nib << (i * 4);
    }
    cm[((size_t)b * 32 + kb) * SEQ + s] = bits;
    if (bits != ~0ull)
        atomicOr(&msum[(b << 4) | (s >> 7)], 1u << kb);
}

// ---------------------------------------------------------------------------
// Shared GEMM tile body: C[128x128] += A[r0..] * W[c0..]^T, bf16 MFMA.
// A,W row-major bf16 with K stride 1024. Per-wave 64x64 = 4x4 C-frags.
// LDS rows (128 B) are XOR-ROTATED by row index: phys 16B-group p of row r
// holds logical group (p - r) & 7 (rotation folded into the GLOBAL source
// address, since global_load_lds's LDS side is fixed base + lane*16).
// Fragment reads use group ((ks*4+quad) + row) & 7 -> consecutive rows hit
// rotated bank groups (2-way aliasing = free) instead of 16 rows on one
// bank group (the 9.4e6-conflict hotspot measured in R8).
// ---------------------------------------------------------------------------
__device__ __forceinline__ void gemm_body(
    const unsigned short* A, const unsigned short* W, int r0, int c0,
    unsigned short* As, unsigned short* Bs, f32x4 acc[4][4])
{
    const int tid  = threadIdx.x;
    const int wave = tid >> 6, lane = tid & 63;
    const int quad = lane >> 4, l15 = lane & 15;
    const int wr = wave >> 1, wc = wave & 1;
    for (int k0 = 0; k0 < DMODEL; k0 += 64) {
        __syncthreads();
        #pragma unroll
        for (int r = 0; r < 4; r++) {
            int f   = r * 4096 + tid * 16;    // byte offset in 16KB tile
            int row = f >> 7;                 // tile row 0..127
            int g   = (((f >> 4) & 7) - row) & 7;   // logical group at this slot
            gl_lds16((const char*)A + (size_t)(r0 + row) * 2048 + k0 * 2 + g * 16,
                     (char*)As + r * 4096 + wave * 1024);
            gl_lds16((const char*)W + (size_t)(c0 + row) * 2048 + k0 * 2 + g * 16,
                     (char*)Bs + r * 4096 + wave * 1024);
        }
        __syncthreads();
        #pragma unroll
        for (int ks = 0; ks < 2; ks++) {
            s16x8 a[4], b[4];
            #pragma unroll
            for (int mt = 0; mt < 4; mt++) {
                int row = wr*64 + mt*16 + l15;
                a[mt] = *(const s16x8*)((const char*)As + row * 128 + ((ks*4 + quad + row) & 7) * 16);
            }
            #pragma unroll
            for (int nt = 0; nt < 4; nt++) {
                int row = wc*64 + nt*16 + l15;
                b[nt] = *(const s16x8*)((const char*)Bs + row * 128 + ((ks*4 + quad + row) & 7) * 16);
            }
            #pragma unroll
            for (int mt = 0; mt < 4; mt++)
                #pragma unroll
                for (int nt = 0; nt < 4; nt++)
                    acc[mt][nt] = __builtin_amdgcn_mfma_f32_16x16x32_bf16(a[mt], b[nt], acc[mt][nt], 0, 0, 0);
        }
    }
}

// ---------------------------------------------------------------------------
// QKV projections: z=0 -> q (scaled, [B,H,S,d]), z=1 -> k ([B,H,S,d]),
// z=2 -> V^T computed DIRECTLY as Wv * X^T (operand swap, coalesced stores).
// ---------------------------------------------------------------------------
__global__ __launch_bounds__(256) void qkv_gemm_kernel(
    unsigned short* __restrict__ ws,
    const float* __restrict__ bq, const float* __restrict__ bk, const float* __restrict__ bv)
{
    __shared__ __align__(16) unsigned short As[8192];
    __shared__ __align__(16) unsigned short Bs[8192];
    const int z = blockIdx.z;
    const unsigned short *A, *W;
    int r0, c0;
    if (z != 2) {
        A = ws + (size_t)z * 4194304;            // xq/xk
        W = ws + OFF_WQ + (size_t)z * 1048576;
        r0 = blockIdx.x * 128; c0 = blockIdx.y * 128;
    } else {
        A = ws + OFF_WV;                         // rows = output features
        W = ws + OFF_XV;                         // "cols" = seq rows
        r0 = blockIdx.y * 128; c0 = blockIdx.x * 128;
    }
    const float* bias = (z == 0) ? bq : (z == 1 ? bk : bv);
    unsigned short* outp = ws + OFF_QB + (size_t)z * 4194304;      // qb/kb/vt
    const float scale = (z == 0) ? QSCALE : 1.0f;

    f32x4 acc[4][4] = {};
    gemm_body(A, W, r0, c0, As, Bs, acc);

    const int lane = threadIdx.x & 63, wave = threadIdx.x >> 6;
    const int quad = lane >> 4, l15 = lane & 15;
    const int wr = wave >> 1, wc = wave & 1;
    if (z != 2) {
        float bias_v[4];
        #pragma unroll
        for (int nt = 0; nt < 4; nt++) bias_v[nt] = bias[c0 + wc*64 + nt*16 + l15];
        #pragma unroll
        for (int mt = 0; mt < 4; mt++) {
            #pragma unroll
            for (int nt = 0; nt < 4; nt++) {
                int c = c0 + wc*64 + nt*16 + l15;
                int hh = c >> 6, dd = c & 63;
                #pragma unroll
                for (int reg = 0; reg < 4; reg++) {
                    int r = r0 + wr*64 + mt*16 + quad*4 + reg;
                    int bb = r >> 11, ss = r & (SEQ - 1);
                    float val = (acc[mt][nt][reg] + bias_v[nt]) * scale;
                    outp[(((size_t)(bb*NHEAD + hh)) * SEQ + ss) * HDIM + dd] = f2bf(val);
                }
            }
        }
    } else {
        #pragma unroll
        for (int mt = 0; mt < 4; mt++) {
            #pragma unroll
            for (int reg = 0; reg < 4; reg++) {
                int f = r0 + wr*64 + mt*16 + quad*4 + reg;   // feature
                int hh = f >> 6, dd = f & 63;
                float bfv = bias[f];
                #pragma unroll
                for (int nt = 0; nt < 4; nt++) {
                    int r = c0 + wc*64 + nt*16 + l15;        // seq row
                    int bb = r >> 11, ss = r & (SEQ - 1);
                    outp[(((size_t)(bb*NHEAD + hh)) * HDIM + dd) * SEQ + ss] =
                        f2bf(acc[mt][nt][reg] + bfv);
                }
            }
        }
    }
}

// ---------------------------------------------------------------------------
// Out projection: out = ab @ Wo^T + bo + residual  (fp32 out)
// ---------------------------------------------------------------------------
__global__ __launch_bounds__(256) void oproj_gemm_kernel(
    const unsigned short* __restrict__ ws, const float* __restrict__ bo,
    const float* __restrict__ resid, float* __restrict__ outf)
{
    __shared__ __align__(16) unsigned short As[8192];
    __shared__ __align__(16) unsigned short Bs[8192];
    const unsigned short* A = ws + OFF_XQ;      // ab lives where xq was
    const unsigned short* W = ws + OFF_WO;
    const int r0 = blockIdx.x * 128, c0 = blockIdx.y * 128;

    f32x4 acc[4][4] = {};
    gemm_body(A, W, r0, c0, (unsigned short*)As, (unsigned short*)Bs, acc);

    const int lane = threadIdx.x & 63, wave = threadIdx.x >> 6;
    const int quad = lane >> 4, l15 = lane & 15;
    const int wr = wave >> 1, wc = wave & 1;
    #pragma unroll
    for (int mt = 0; mt < 4; mt++) {
        #pragma unroll
        for (int nt = 0; nt < 4; nt++) {
            int c = c0 + wc*64 + nt*16 + l15;
            float bv = bo[c];
            #pragma unroll
            for (int reg = 0; reg < 4; reg++) {
                int r = r0 + wr*64 + mt*16 + quad*4 + reg;
                size_t idx = (size_t)r * DMODEL + c;
                outf[idx] = acc[mt][nt][reg] + bv + resid[idx];
            }
        }
    }
}

// ---------------------------------------------------------------------------
// Flash attention, bf16 MFMA, static softmax.
// R11 = R5 skeleton (512 thr, 8 waves x 16 q-rows, K+V LDS double-buffered,
// 2 blocks/CU -- proven 65.4us; R9 showed occupancy must stay, R10 showed
// register prefetch doesn't survive the compiler) + SWAPPED QK^T softmax
// path: compute mfma(K, Q) instead of mfma(Q, K). Both operands have the
// identical per-lane layout (row=l15, k-octet=quad) so the same fragments
// work; output flips to S^T[key=kt*16+quad*4+reg][q=l15], making 4
// consecutive KEYS lane-local. This turns the P spill into 4 ds_write_b64
// (was 16 ds_write_b16), makes l a lane-local scalar accumulate (drops the
// 2 ones-column MFMAs/chunk; same truncated-bf16 values summed, so numerics
// match), and the mask fetch one u64/lane (was 4). LDS-port model:
// 325 -> ~280 cy/wave-chunk vs R5's saturated 166K cy/CU.
// ---------------------------------------------------------------------------
__global__ __launch_bounds__(512) void attn_mfma_kernel(
    const unsigned short* __restrict__ ws,
    const unsigned long long* __restrict__ cmask,
    const unsigned int* __restrict__ msum,
    unsigned short* __restrict__ ab)
{
    const int tid  = threadIdx.x;
    const int wave = tid >> 6, lane = tid & 63;
    const int quad = lane >> 4, l15 = lane & 15;
    const int h = blockIdx.y, b = blockIdx.z;
    const int qw = blockIdx.x * 128 + wave * 16;

    const char* qh = (const char*)(ws + OFF_QB + ((size_t)(b*NHEAD + h)) * SEQ * HDIM);
    const char* kh = (const char*)(ws + OFF_KB + ((size_t)(b*NHEAD + h)) * SEQ * HDIM);
    const char* vh = (const char*)(ws + OFF_VT + ((size_t)(b*NHEAD + h)) * SEQ * HDIM);

    __shared__ __align__(16) char Ks[2][8192];   // [key][d] rows, groups rotated
    __shared__ __align__(16) char Vs[2][8192];   // [d][key] rows, groups rotated
    __shared__ __align__(16) unsigned short Pl[8][16 * 72];
    unsigned short* Pw = Pl[wave];

    const unsigned int chunkflags = msum[(b << 4) | blockIdx.x];

    // staging: 512 threads x 16B = one 8KB buffer per call; row = tid>>3,
    // phys group tid&7 holds logical group ((tid&7) - row) & 7 (XOR-rotate)
    const int srow = tid >> 3;
    const int sgrp = ((tid & 7) - srow) & 7;

    #define STAGE(bf, k0)                                                       \
        do {                                                                    \
            gl_lds16(kh + (size_t)((k0) + srow) * 128 + sgrp * 16,              \
                     Ks[bf] + wave * 1024);                                     \
            gl_lds16(vh + (size_t)srow * 4096 + (size_t)(k0) * 2 + sgrp * 16,   \
                     Vs[bf] + wave * 1024);                                     \
        } while (0)

    s16x8 qa[2];
    #pragma unroll
    for (int ks = 0; ks < 2; ks++)
        qa[ks] = *(const s16x8*)(qh + (size_t)(qw + l15) * 128 + ks*64 + quad*16);

    f32x4 o[4];
    #pragma unroll
    for (int nt = 0; nt < 4; nt++) o[nt] = (f32x4){0.f, 0.f, 0.f, 0.f};
    float lpart = 0.f;   // lane-local softmax denominator partial (16 keys/lane/chunk)

    STAGE(0, 0);
    int bf = 0;
    for (int k0 = 0; k0 < SEQ; k0 += 64) {
        __syncthreads();            // vmcnt(0): buf[bf] staged, buf[bf^1] free
        // prefetch next chunk into the other buffer
        if (k0 + 64 < SEQ) STAGE(bf ^ 1, k0 + 64);

        const char* Kb = Ks[bf];
        const char* Vb = Vs[bf];
        // --- S^T = K Q^T (exp2-domain, pre-scaled); swapped operands:
        //     st[kt][reg] = S[key = kt*16+quad*4+reg][q = qw+l15] ---
        f32x4 st[4];
        #pragma unroll
        for (int kt = 0; kt < 4; kt++) {
            int keyrow = kt*16 + l15;
            s16x8 kf0 = *(const s16x8*)(Kb + keyrow*128 + ((quad     + keyrow) & 7) * 16);
            s16x8 kf1 = *(const s16x8*)(Kb + keyrow*128 + ((4 + quad + keyrow) & 7) * 16);
            f32x4 z = {0.f, 0.f, 0.f, 0.f};
            st[kt] = __builtin_amdgcn_mfma_f32_16x16x32_bf16(kf0, qa[0], z, 0, 0, 0);
            st[kt] = __builtin_amdgcn_mfma_f32_16x16x32_bf16(kf1, qa[1], st[kt], 0, 0, 0);
        }
        // --- mask: one u64 per lane (q = qw+l15), bits indexed by key ---
        if (chunkflags & (1u << (k0 >> 6))) {
            unsigned long long cm =
                cmask[((size_t)b*32 + (k0 >> 6)) * SEQ + qw + l15];
            if (cm != ~0ull) {
                #pragma unroll
                for (int kt = 0; kt < 4; kt++)
                    #pragma unroll
                    for (int reg = 0; reg < 4; reg++) {
                        int key = kt*16 + quad*4 + reg;
                        if (!((cm >> key) & 1)) st[kt][reg] = -1e9f;
                    }
            }
        }
        // --- P = exp2(S) -> LDS as packed b64 (4 adjacent keys per lane);
        //     accumulate the SAME truncated-bf16 values into lpart ---
        #pragma unroll
        for (int kt = 0; kt < 4; kt++) {
            unsigned int pb[4];
            #pragma unroll
            for (int reg = 0; reg < 4; reg++) {
                float pv = exp2f(st[kt][reg]);
                pb[reg] = __builtin_bit_cast(unsigned int, pv) & 0xffff0000u; // trunc
                lpart += __builtin_bit_cast(float, pb[reg]);
            }
            uint2 pk;
            pk.x = (pb[0] >> 16) | pb[1];
            pk.y = (pb[2] >> 16) | pb[3];
            // row = q = l15 (144B stride), cols = keys kt*16+quad*4..+3
            *(uint2*)((char*)Pw + l15 * 144 + kt*32 + quad*8) = pk;
        }
        // --- O += P @ V (A = P rows=q, B = V^T cols=d) ---
        #pragma unroll
        for (int ks = 0; ks < 2; ks++) {
            s16x8 pa = *(const s16x8*)((const char*)Pw + l15 * 144 + ks*64 + quad*16);
            #pragma unroll
            for (int nt = 0; nt < 4; nt++) {
                int d = nt*16 + l15;
                s16x8 vf = *(const s16x8*)(Vb + d*128 + ((ks*4 + quad + d) & 7) * 16);
                o[nt] = __builtin_amdgcn_mfma_f32_16x16x32_bf16(pa, vf, o[nt], 0, 0, 0);
            }
        }
        bf ^= 1;
    }
    #undef STAGE
    // --- finalize l: lane (quad,l15) has partial over its 16 keys/chunk;
    //     sum across the 4 quads -> every lane holds l(q = qw+l15) ---
    lpart += __shfl_xor(lpart, 16);
    lpart += __shfl_xor(lpart, 32);
    // --- epilogue: O / l -> ab [B,S,DMODEL] bf16.
    //     O rows are q = qw+quad*4+reg; l for that q lives at lane quad*4+reg ---
    #pragma unroll
    for (int reg = 0; reg < 4; reg++) {
        float lv = __shfl(lpart, quad*4 + reg);
        float inv = 1.f / lv;
        int sg = qw + quad*4 + reg;
        #pragma unroll
        for (int nt = 0; nt < 4; nt++) {
            size_t idx = ((size_t)b * SEQ + sg) * DMODEL + h*HDIM + nt*16 + l15;
            ab[idx] = f2bf(o[nt][reg] * inv);
        }
    }
}

// ---------------------------------------------------------------------------
// LayerNorm (unbiased std, (std+eps) denominator), in-place on fp32 rows
// ---------------------------------------------------------------------------
__global__ __launch_bounds__(256) void ln_kernel(
    float* __restrict__ x, const float* __restrict__ gamma,
    const float* __restrict__ beta)
{
    const int row = blockIdx.x;
    const int tid = threadIdx.x;
    float4 vals = *(const float4*)&x[(size_t)row * DMODEL + tid * 4];
    float s  = vals.x + vals.y + vals.z + vals.w;
    float ss = vals.x*vals.x + vals.y*vals.y + vals.z*vals.z + vals.w*vals.w;
    #pragma unroll
    for (int off = 32; off > 0; off >>= 1) {
        s  += __shfl_down(s, off);
        ss += __shfl_down(ss, off);
    }
    __shared__ float sbuf[4], ssbuf[4];
    __shared__ float mean_s, inv_s;
    if ((tid & 63) == 0) { sbuf[tid >> 6] = s; ssbuf[tid >> 6] = ss; }
    __syncthreads();
    if (tid == 0) {
        float S1 = 0.f, S2 = 0.f;
        #pragma unroll
        for (int i = 0; i < 4; i++) { S1 += sbuf[i]; S2 += ssbuf[i]; }
        float mean = S1 * (1.0f / DMODEL);
        float var  = (S2 - (float)DMODEL * mean * mean) * (1.0f / (DMODEL - 1));
        float sd   = sqrtf(fmaxf(var, 0.f));
        mean_s = mean;
        inv_s  = 1.f / (sd + EPS);
    }
    __syncthreads();
    float4 g  = *(const float4*)&gamma[tid * 4];
    float4 bt = *(const float4*)&beta[tid * 4];
    float4 o;
    o.x = g.x * (vals.x - mean_s) * inv_s + bt.x;
    o.y = g.y * (vals.y - mean_s) * inv_s + bt.y;
    o.z = g.z * (vals.z - mean_s) * inv_s + bt.z;
    o.w = g.w * (vals.w - mean_s) * inv_s + bt.w;
    *(float4*)&x[(size_t)row * DMODEL + tid * 4] = o;
}

extern "C" void kernel_launch(void* const* d_in, const int* in_sizes, int n_in,
                              void* d_out, int out_size, void* d_ws, size_t ws_size,
                              hipStream_t stream) {
    const float* query = (const float*)d_in[0];
    const float* key   = (const float*)d_in[1];
    const float* value = (const float*)d_in[2];
    const int*   mask  = (const int*)d_in[3];
    const float* Wq = (const float*)d_in[4];  const float* bq = (const float*)d_in[5];
    const float* Wk = (const float*)d_in[6];  const float* bk = (const float*)d_in[7];
    const float* Wv = (const float*)d_in[8];  const float* bv = (const float*)d_in[9];
    const float* Wo = (const float*)d_in[10]; const float* bo = (const float*)d_in[11];
    const float* gamma = (const float*)d_in[12];
    const float* beta  = (const float*)d_in[13];
    float* out = (float*)d_out;

    unsigned short* ws = (unsigned short*)d_ws;
    unsigned long long* cmask = (unsigned long long*)(ws + OFF_CM);
    unsigned int* msum = (unsigned int*)(ws + OFF_MS);

    conv_all_kernel<<<16384, 256, 0, stream>>>(query, key, value, Wq, Wk, Wv, Wo, ws);
    mask_compress_kernel<<<512, 256, 0, stream>>>(mask, cmask, msum);
    qkv_gemm_kernel<<<dim3(32, 8, 3), 256, 0, stream>>>(ws, bq, bk, bv);
    attn_mfma_kernel<<<dim3(SEQ/128, NHEAD, BATCH), 512, 0, stream>>>(ws, cmask, msum, ws + OFF_XQ);
    oproj_gemm_kernel<<<dim3(32, 8), 256, 0, stream>>>(ws, bo, query, out);
    ln_kernel<<<NROWS, 256, 0, stream>>>(out, gamma, beta);
}

// Round 4
// 278.980 us; speedup vs baseline: 1.2648x; 1.0292x over previous
//
#include <hip/hip_runtime.h>
#include <hip/hip_bf16.h>
#include <math.h>
#include <stdint.h>

#define BATCH 2
#define SEQ   2048
#define DMODEL 1024
#define NHEAD 16
#define HDIM  64
#define NROWS (BATCH*SEQ)          // 4096
#define EPS   1e-6f
#define QSCALE 0.1803368801111204f // 0.125 * log2(e): softmax in exp2 domain

typedef float f32x4 __attribute__((ext_vector_type(4)));
typedef short s16x8 __attribute__((ext_vector_type(8)));
typedef unsigned int u32x4 __attribute__((ext_vector_type(4)));

// ws layout (ushort units):
//  xq @ 0            (4194304)   -> reused as ab (attention out) after projections
//  xk @ 4194304
//  xv @ 8388608
//  wq @ 12582912     (1048576 each)
//  wk @ 13631488
//  wv @ 14680064
//  wo @ 15728640
//  qb @ 16777216     [B,H,S,64] bf16, pre-scaled by QSCALE
//  kb @ 20971520     [B,H,S,64] bf16
//  vt @ 25165824     [B,H,64,S] bf16 (V transposed)
//  cmask @ 29360128  (1 MB): [B][32 kblocks][S] uint64 bitmask
//  msum  @ 29884416  (128 B): [B][16 qb128] uint32, bit kb = "has masked"
#define OFF_XQ 0
#define OFF_XK 4194304
#define OFF_XV 8388608
#define OFF_WQ 12582912
#define OFF_WK 13631488
#define OFF_WV 14680064
#define OFF_WO 15728640
#define OFF_QB 16777216
#define OFF_KB 20971520
#define OFF_VT 25165824
#define OFF_CM 29360128
#define OFF_MS 29884416

__device__ __forceinline__ unsigned short f2bf(float x) {
    unsigned int u = __builtin_bit_cast(unsigned int, x);
    u += 0x7fff + ((u >> 16) & 1);            // round-to-nearest-even
    return (unsigned short)(u >> 16);
}

__device__ __forceinline__ void gl_lds16(const void* g, void* l) {
    __builtin_amdgcn_global_load_lds(
        (const __attribute__((address_space(1))) unsigned int*)g,
        (__attribute__((address_space(3))) unsigned int*)(unsigned int)(unsigned long long)l,
        16, 0, 0);
}

// ---------------------------------------------------------------------------
// fused fp32 -> bf16 convert of query/key/value + 4 weight matrices
// (also zero-inits the mask summary words for the following dispatch)
// ---------------------------------------------------------------------------
__global__ __launch_bounds__(256) void conv_all_kernel(
    const float* __restrict__ q, const float* __restrict__ k, const float* __restrict__ v,
    const float* __restrict__ wq, const float* __restrict__ wk, const float* __restrict__ wv,
    const float* __restrict__ wo, unsigned short* __restrict__ ws)
{
    if (blockIdx.x == 0 && threadIdx.x < 32)
        ((unsigned int*)(ws + OFF_MS))[threadIdx.x] = 0;
    size_t t = ((size_t)blockIdx.x * 256 + threadIdx.x) * 4;
    const float* src; unsigned short* dst; size_t off;
    if (t < 4194304)       { src = q;  dst = ws + OFF_XQ; off = t; }
    else if (t < 8388608)  { src = k;  dst = ws + OFF_XK; off = t - 4194304; }
    else if (t < 12582912) { src = v;  dst = ws + OFF_XV; off = t - 8388608; }
    else if (t < 13631488) { src = wq; dst = ws + OFF_WQ; off = t - 12582912; }
    else if (t < 14680064) { src = wk; dst = ws + OFF_WK; off = t - 13631488; }
    else if (t < 15728640) { src = wv; dst = ws + OFF_WV; off = t - 14680064; }
    else                   { src = wo; dst = ws + OFF_WO; off = t - 15728640; }
    float4 x = *(const float4*)&src[off];
    ushort4 o;
    o.x = f2bf(x.x); o.y = f2bf(x.y); o.z = f2bf(x.z); o.w = f2bf(x.w);
    *(ushort4*)&dst[off] = o;
}

// ---------------------------------------------------------------------------
// mask -> per-(b, kblock, s) 64-bit bitmask + per-(b, qb128) chunk summary
// ---------------------------------------------------------------------------
__global__ __launch_bounds__(256) void mask_compress_kernel(
    const int* __restrict__ mask, unsigned long long* __restrict__ cm,
    unsigned int* __restrict__ msum)
{
    int t = blockIdx.x * 256 + threadIdx.x;  // [0, 2*32*2048)
    int s  = t & 2047;
    int kb = (t >> 11) & 31;
    int b  = t >> 16;
    const int* mp = mask + ((size_t)b * SEQ + s) * SEQ + kb * 64;
    unsigned long long bits = 0;
    #pragma unroll
    for (int i = 0; i < 16; i++) {
        int4 m4 = *(const int4*)&mp[i * 4];
        unsigned long long nib =
            (unsigned long long)((m4.x != 0) | ((m4.y != 0) << 1) |
                                 ((m4.z != 0) << 2) | ((m4.w != 0) << 3));
        bits |= nib << (i * 4);
    }
    cm[((size_t)b * 32 + kb) * SEQ + s] = bits;
    if (bits != ~0ull)
        atomicOr(&msum[(b << 4) | (s >> 7)], 1u << kb);
}

// ---------------------------------------------------------------------------
// Shared GEMM tile body: C[128x128] += A[r0..] * W[c0..]^T, bf16 MFMA.
// A,W row-major bf16 with K stride 1024. Per-wave 64x64 = 4x4 C-frags.
// LDS rows (128 B) are XOR-ROTATED by row index: phys 16B-group p of row r
// holds logical group (p - r) & 7 (rotation folded into the GLOBAL source
// address, since global_load_lds's LDS side is fixed base + lane*16).
// Fragment reads use group ((ks*4+quad) + row) & 7 -> consecutive rows hit
// rotated bank groups (2-way aliasing = free) instead of 16 rows on one
// bank group (the 9.4e6-conflict hotspot measured in R8).
// ---------------------------------------------------------------------------
__device__ __forceinline__ void gemm_body(
    const unsigned short* A, const unsigned short* W, int r0, int c0,
    unsigned short* As, unsigned short* Bs, f32x4 acc[4][4])
{
    const int tid  = threadIdx.x;
    const int wave = tid >> 6, lane = tid & 63;
    const int quad = lane >> 4, l15 = lane & 15;
    const int wr = wave >> 1, wc = wave & 1;
    for (int k0 = 0; k0 < DMODEL; k0 += 64) {
        __syncthreads();
        #pragma unroll
        for (int r = 0; r < 4; r++) {
            int f   = r * 4096 + tid * 16;    // byte offset in 16KB tile
            int row = f >> 7;                 // tile row 0..127
            int g   = (((f >> 4) & 7) - row) & 7;   // logical group at this slot
            gl_lds16((const char*)A + (size_t)(r0 + row) * 2048 + k0 * 2 + g * 16,
                     (char*)As + r * 4096 + wave * 1024);
            gl_lds16((const char*)W + (size_t)(c0 + row) * 2048 + k0 * 2 + g * 16,
                     (char*)Bs + r * 4096 + wave * 1024);
        }
        __syncthreads();
        #pragma unroll
        for (int ks = 0; ks < 2; ks++) {
            s16x8 a[4], b[4];
            #pragma unroll
            for (int mt = 0; mt < 4; mt++) {
                int row = wr*64 + mt*16 + l15;
                a[mt] = *(const s16x8*)((const char*)As + row * 128 + ((ks*4 + quad + row) & 7) * 16);
            }
            #pragma unroll
            for (int nt = 0; nt < 4; nt++) {
                int row = wc*64 + nt*16 + l15;
                b[nt] = *(const s16x8*)((const char*)Bs + row * 128 + ((ks*4 + quad + row) & 7) * 16);
            }
            #pragma unroll
            for (int mt = 0; mt < 4; mt++)
                #pragma unroll
                for (int nt = 0; nt < 4; nt++)
                    acc[mt][nt] = __builtin_amdgcn_mfma_f32_16x16x32_bf16(a[mt], b[nt], acc[mt][nt], 0, 0, 0);
        }
    }
}

// ---------------------------------------------------------------------------
// QKV projections: z=0 -> q (scaled, [B,H,S,d]), z=1 -> k ([B,H,S,d]),
// z=2 -> V^T computed DIRECTLY as Wv * X^T (operand swap, coalesced stores).
// ---------------------------------------------------------------------------
__global__ __launch_bounds__(256) void qkv_gemm_kernel(
    unsigned short* __restrict__ ws,
    const float* __restrict__ bq, const float* __restrict__ bk, const float* __restrict__ bv)
{
    __shared__ __align__(16) unsigned short As[8192];
    __shared__ __align__(16) unsigned short Bs[8192];
    const int z = blockIdx.z;
    const unsigned short *A, *W;
    int r0, c0;
    if (z != 2) {
        A = ws + (size_t)z * 4194304;            // xq/xk
        W = ws + OFF_WQ + (size_t)z * 1048576;
        r0 = blockIdx.x * 128; c0 = blockIdx.y * 128;
    } else {
        A = ws + OFF_WV;                         // rows = output features
        W = ws + OFF_XV;                         // "cols" = seq rows
        r0 = blockIdx.y * 128; c0 = blockIdx.x * 128;
    }
    const float* bias = (z == 0) ? bq : (z == 1 ? bk : bv);
    unsigned short* outp = ws + OFF_QB + (size_t)z * 4194304;      // qb/kb/vt
    const float scale = (z == 0) ? QSCALE : 1.0f;

    f32x4 acc[4][4] = {};
    gemm_body(A, W, r0, c0, As, Bs, acc);

    const int lane = threadIdx.x & 63, wave = threadIdx.x >> 6;
    const int quad = lane >> 4, l15 = lane & 15;
    const int wr = wave >> 1, wc = wave & 1;
    if (z != 2) {
        float bias_v[4];
        #pragma unroll
        for (int nt = 0; nt < 4; nt++) bias_v[nt] = bias[c0 + wc*64 + nt*16 + l15];
        #pragma unroll
        for (int mt = 0; mt < 4; mt++) {
            #pragma unroll
            for (int nt = 0; nt < 4; nt++) {
                int c = c0 + wc*64 + nt*16 + l15;
                int hh = c >> 6, dd = c & 63;
                #pragma unroll
                for (int reg = 0; reg < 4; reg++) {
                    int r = r0 + wr*64 + mt*16 + quad*4 + reg;
                    int bb = r >> 11, ss = r & (SEQ - 1);
                    float val = (acc[mt][nt][reg] + bias_v[nt]) * scale;
                    outp[(((size_t)(bb*NHEAD + hh)) * SEQ + ss) * HDIM + dd] = f2bf(val);
                }
            }
        }
    } else {
        #pragma unroll
        for (int mt = 0; mt < 4; mt++) {
            #pragma unroll
            for (int reg = 0; reg < 4; reg++) {
                int f = r0 + wr*64 + mt*16 + quad*4 + reg;   // feature
                int hh = f >> 6, dd = f & 63;
                float bfv = bias[f];
                #pragma unroll
                for (int nt = 0; nt < 4; nt++) {
                    int r = c0 + wc*64 + nt*16 + l15;        // seq row
                    int bb = r >> 11, ss = r & (SEQ - 1);
                    outp[(((size_t)(bb*NHEAD + hh)) * HDIM + dd) * SEQ + ss] =
                        f2bf(acc[mt][nt][reg] + bfv);
                }
            }
        }
    }
}

// ---------------------------------------------------------------------------
// Out projection: out = ab @ Wo^T + bo + residual  (fp32 out)
// ---------------------------------------------------------------------------
__global__ __launch_bounds__(256) void oproj_gemm_kernel(
    const unsigned short* __restrict__ ws, const float* __restrict__ bo,
    const float* __restrict__ resid, float* __restrict__ outf)
{
    __shared__ __align__(16) unsigned short As[8192];
    __shared__ __align__(16) unsigned short Bs[8192];
    const unsigned short* A = ws + OFF_XQ;      // ab lives where xq was
    const unsigned short* W = ws + OFF_WO;
    const int r0 = blockIdx.x * 128, c0 = blockIdx.y * 128;

    f32x4 acc[4][4] = {};
    gemm_body(A, W, r0, c0, (unsigned short*)As, (unsigned short*)Bs, acc);

    const int lane = threadIdx.x & 63, wave = threadIdx.x >> 6;
    const int quad = lane >> 4, l15 = lane & 15;
    const int wr = wave >> 1, wc = wave & 1;
    #pragma unroll
    for (int mt = 0; mt < 4; mt++) {
        #pragma unroll
        for (int nt = 0; nt < 4; nt++) {
            int c = c0 + wc*64 + nt*16 + l15;
            float bv = bo[c];
            #pragma unroll
            for (int reg = 0; reg < 4; reg++) {
                int r = r0 + wr*64 + mt*16 + quad*4 + reg;
                size_t idx = (size_t)r * DMODEL + c;
                outf[idx] = acc[mt][nt][reg] + bv + resid[idx];
            }
        }
    }
}

// ---------------------------------------------------------------------------
// Flash attention, bf16 MFMA, static softmax.
// R12 = R5 skeleton (512 thr, 8 waves x 16 q-rows, K+V LDS double-buffered,
// 2 blocks/CU) + swapped QK^T (R11-verified) + KEY-PERMUTED K STAGING so
// P stays entirely in registers:
//   LDS K row p holds global key a(p), a = bit-permute [p5][p3 p2][p4][p1 p0]
//   => C-slot (kt,quad,reg) of S^T holds actual key
//      (kt>>1)*32 + quad*8 + (kt&1)*4 + reg
//   which is EXACTLY the PV A-operand key octet (quad*8..+7 per ks).
// So P = exp2(S) is packed per-lane (trunc to bf16, 4 dwords) and fed
// straight to the PV MFMA: no P LDS write/read at all (was 117 of 325
// LDS-port cy/wave-chunk in R5; R11's packed P-writes were the 3.1M-conflict
// hotspot). l accumulates lane-locally on the same truncated values
// (bias cancels in P/l); mask uses the permuted key index. Pl buffer
// deleted (LDS 51200 -> 32768 B).
// ---------------------------------------------------------------------------
__global__ __launch_bounds__(512) void attn_mfma_kernel(
    const unsigned short* __restrict__ ws,
    const unsigned long long* __restrict__ cmask,
    const unsigned int* __restrict__ msum,
    unsigned short* __restrict__ ab)
{
    const int tid  = threadIdx.x;
    const int wave = tid >> 6, lane = tid & 63;
    const int quad = lane >> 4, l15 = lane & 15;
    const int h = blockIdx.y, b = blockIdx.z;
    const int qw = blockIdx.x * 128 + wave * 16;

    const char* qh = (const char*)(ws + OFF_QB + ((size_t)(b*NHEAD + h)) * SEQ * HDIM);
    const char* kh = (const char*)(ws + OFF_KB + ((size_t)(b*NHEAD + h)) * SEQ * HDIM);
    const char* vh = (const char*)(ws + OFF_VT + ((size_t)(b*NHEAD + h)) * SEQ * HDIM);

    __shared__ __align__(16) char Ks[2][8192];   // [perm key][d] rows, groups rotated
    __shared__ __align__(16) char Vs[2][8192];   // [d][key] rows, groups rotated

    const unsigned int chunkflags = msum[(b << 4) | blockIdx.x];

    // staging: 512 threads x 16B = one 8KB buffer per call; LDS row = tid>>3,
    // phys group tid&7 holds logical group ((tid&7) - row) & 7 (XOR-rotate).
    // K source row is the PERMUTED key a(row): bits [r5][r3 r2][r4][r1 r0].
    const int srow = tid >> 3;
    const int sgrp = ((tid & 7) - srow) & 7;
    const int arow = (srow & 0x23) | ((srow & 0x0C) << 1) | ((srow & 0x10) >> 2);

    #define STAGE(bf, k0)                                                       \
        do {                                                                    \
            gl_lds16(kh + (size_t)((k0) + arow) * 128 + sgrp * 16,              \
                     Ks[bf] + wave * 1024);                                     \
            gl_lds16(vh + (size_t)srow * 4096 + (size_t)(k0) * 2 + sgrp * 16,   \
                     Vs[bf] + wave * 1024);                                     \
        } while (0)

    s16x8 qa[2];
    #pragma unroll
    for (int ks = 0; ks < 2; ks++)
        qa[ks] = *(const s16x8*)(qh + (size_t)(qw + l15) * 128 + ks*64 + quad*16);

    f32x4 o[4];
    #pragma unroll
    for (int nt = 0; nt < 4; nt++) o[nt] = (f32x4){0.f, 0.f, 0.f, 0.f};
    float lpart = 0.f;   // lane-local softmax denominator partial (16 keys/lane/chunk)

    STAGE(0, 0);
    int bf = 0;
    for (int k0 = 0; k0 < SEQ; k0 += 64) {
        __syncthreads();            // vmcnt(0): buf[bf] staged, buf[bf^1] free
        // prefetch next chunk into the other buffer
        if (k0 + 64 < SEQ) STAGE(bf ^ 1, k0 + 64);

        const char* Kb = Ks[bf];
        const char* Vb = Vs[bf];
        // --- S^T = K Q^T (exp2-domain, pre-scaled), K as A-operand from the
        //     permuted LDS rows; st[kt][reg] = S[key a(kt*16+quad*4+reg)][q=l15]
        f32x4 st[4];
        #pragma unroll
        for (int kt = 0; kt < 4; kt++) {
            int prow = kt*16 + l15;   // permuted LDS row (rotation by LDS row)
            s16x8 kf0 = *(const s16x8*)(Kb + prow*128 + ((quad     + prow) & 7) * 16);
            s16x8 kf1 = *(const s16x8*)(Kb + prow*128 + ((4 + quad + prow) & 7) * 16);
            f32x4 z = {0.f, 0.f, 0.f, 0.f};
            st[kt] = __builtin_amdgcn_mfma_f32_16x16x32_bf16(kf0, qa[0], z, 0, 0, 0);
            st[kt] = __builtin_amdgcn_mfma_f32_16x16x32_bf16(kf1, qa[1], st[kt], 0, 0, 0);
        }
        // --- mask: one u64 per lane (q = qw+l15), bit = PERMUTED key index ---
        if (chunkflags & (1u << (k0 >> 6))) {
            unsigned long long cm =
                cmask[((size_t)b*32 + (k0 >> 6)) * SEQ + qw + l15];
            if (cm != ~0ull) {
                #pragma unroll
                for (int kt = 0; kt < 4; kt++)
                    #pragma unroll
                    for (int reg = 0; reg < 4; reg++) {
                        int key = (kt >> 1)*32 + quad*8 + (kt & 1)*4 + reg;
                        if (!((cm >> key) & 1)) st[kt][reg] = -1e9f;
                    }
            }
        }
        // --- P = exp2(S) packed IN-REGISTER (trunc bf16; bias cancels in P/l);
        //     lane holds exactly keys ks*32+quad*8..+7 = the PV A-octets ---
        #pragma unroll
        for (int ks = 0; ks < 2; ks++) {
            unsigned int pb[8];
            #pragma unroll
            for (int j = 0; j < 8; j++) {
                int kt = 2*ks + (j >> 2), r = j & 3;
                float pv = exp2f(st[kt][r]);
                unsigned int u = __builtin_bit_cast(unsigned int, pv) & 0xffff0000u;
                pb[j] = u;
                lpart += __builtin_bit_cast(float, u);
            }
            u32x4 pw;
            pw[0] = (pb[0] >> 16) | pb[1];
            pw[1] = (pb[2] >> 16) | pb[3];
            pw[2] = (pb[4] >> 16) | pb[5];
            pw[3] = (pb[6] >> 16) | pb[7];
            s16x8 pa = __builtin_bit_cast(s16x8, pw);
            #pragma unroll
            for (int nt = 0; nt < 4; nt++) {
                int d = nt*16 + l15;
                s16x8 vf = *(const s16x8*)(Vb + d*128 + ((ks*4 + quad + d) & 7) * 16);
                o[nt] = __builtin_amdgcn_mfma_f32_16x16x32_bf16(pa, vf, o[nt], 0, 0, 0);
            }
        }
        bf ^= 1;
    }
    #undef STAGE
    // --- finalize l: lane (quad,l15) has partial over its 16 keys/chunk;
    //     sum across the 4 quads -> every lane holds l(q = qw+l15) ---
    lpart += __shfl_xor(lpart, 16);
    lpart += __shfl_xor(lpart, 32);
    // --- epilogue: O / l -> ab [B,S,DMODEL] bf16.
    //     O rows are q = qw+quad*4+reg; l for that q lives at lane quad*4+reg ---
    #pragma unroll
    for (int reg = 0; reg < 4; reg++) {
        float lv = __shfl(lpart, quad*4 + reg);
        float inv = 1.f / lv;
        int sg = qw + quad*4 + reg;
        #pragma unroll
        for (int nt = 0; nt < 4; nt++) {
            size_t idx = ((size_t)b * SEQ + sg) * DMODEL + h*HDIM + nt*16 + l15;
            ab[idx] = f2bf(o[nt][reg] * inv);
        }
    }
}

// ---------------------------------------------------------------------------
// LayerNorm (unbiased std, (std+eps) denominator), in-place on fp32 rows
// ---------------------------------------------------------------------------
__global__ __launch_bounds__(256) void ln_kernel(
    float* __restrict__ x, const float* __restrict__ gamma,
    const float* __restrict__ beta)
{
    const int row = blockIdx.x;
    const int tid = threadIdx.x;
    float4 vals = *(const float4*)&x[(size_t)row * DMODEL + tid * 4];
    float s  = vals.x + vals.y + vals.z + vals.w;
    float ss = vals.x*vals.x + vals.y*vals.y + vals.z*vals.z + vals.w*vals.w;
    #pragma unroll
    for (int off = 32; off > 0; off >>= 1) {
        s  += __shfl_down(s, off);
        ss += __shfl_down(ss, off);
    }
    __shared__ float sbuf[4], ssbuf[4];
    __shared__ float mean_s, inv_s;
    if ((tid & 63) == 0) { sbuf[tid >> 6] = s; ssbuf[tid >> 6] = ss; }
    __syncthreads();
    if (tid == 0) {
        float S1 = 0.f, S2 = 0.f;
        #pragma unroll
        for (int i = 0; i < 4; i++) { S1 += sbuf[i]; S2 += ssbuf[i]; }
        float mean = S1 * (1.0f / DMODEL);
        float var  = (S2 - (float)DMODEL * mean * mean) * (1.0f / (DMODEL - 1));
        float sd   = sqrtf(fmaxf(var, 0.f));
        mean_s = mean;
        inv_s  = 1.f / (sd + EPS);
    }
    __syncthreads();
    float4 g  = *(const float4*)&gamma[tid * 4];
    float4 bt = *(const float4*)&beta[tid * 4];
    float4 o;
    o.x = g.x * (vals.x - mean_s) * inv_s + bt.x;
    o.y = g.y * (vals.y - mean_s) * inv_s + bt.y;
    o.z = g.z * (vals.z - mean_s) * inv_s + bt.z;
    o.w = g.w * (vals.w - mean_s) * inv_s + bt.w;
    *(float4*)&x[(size_t)row * DMODEL + tid * 4] = o;
}

extern "C" void kernel_launch(void* const* d_in, const int* in_sizes, int n_in,
                              void* d_out, int out_size, void* d_ws, size_t ws_size,
                              hipStream_t stream) {
    const float* query = (const float*)d_in[0];
    const float* key   = (const float*)d_in[1];
    const float* value = (const float*)d_in[2];
    const int*   mask  = (const int*)d_in[3];
    const float* Wq = (const float*)d_in[4];  const float* bq = (const float*)d_in[5];
    const float* Wk = (const float*)d_in[6];  const float* bk = (const float*)d_in[7];
    const float* Wv = (const float*)d_in[8];  const float* bv = (const float*)d_in[9];
    const float* Wo = (const float*)d_in[10]; const float* bo = (const float*)d_in[11];
    const float* gamma = (const float*)d_in[12];
    const float* beta  = (const float*)d_in[13];
    float* out = (float*)d_out;

    unsigned short* ws = (unsigned short*)d_ws;
    unsigned long long* cmask = (unsigned long long*)(ws + OFF_CM);
    unsigned int* msum = (unsigned int*)(ws + OFF_MS);

    conv_all_kernel<<<16384, 256, 0, stream>>>(query, key, value, Wq, Wk, Wv, Wo, ws);
    mask_compress_kernel<<<512, 256, 0, stream>>>(mask, cmask, msum);
    qkv_gemm_kernel<<<dim3(32, 8, 3), 256, 0, stream>>>(ws, bq, bk, bv);
    attn_mfma_kernel<<<dim3(SEQ/128, NHEAD, BATCH), 512, 0, stream>>>(ws, cmask, msum, ws + OFF_XQ);
    oproj_gemm_kernel<<<dim3(32, 8), 256, 0, stream>>>(ws, bo, query, out);
    ln_kernel<<<NROWS, 256, 0, stream>>>(out, gamma, beta);
}

// Round 5
// 275.087 us; speedup vs baseline: 1.2827x; 1.0142x over previous
//
#include <hip/hip_runtime.h>
#include <hip/hip_bf16.h>
#include <math.h>
#include <stdint.h>

#define BATCH 2
#define SEQ   2048
#define DMODEL 1024
#define NHEAD 16
#define HDIM  64
#define NROWS (BATCH*SEQ)          // 4096
#define EPS   1e-6f
#define QSCALE 0.1803368801111204f // 0.125 * log2(e): softmax in exp2 domain

typedef float f32x4 __attribute__((ext_vector_type(4)));
typedef short s16x8 __attribute__((ext_vector_type(8)));
typedef unsigned int u32x4 __attribute__((ext_vector_type(4)));

// ws layout (ushort units):
//  xq @ 0            (4194304)   -> reused as ab (attention out) after projections
//  xk @ 4194304
//  xv @ 8388608
//  wq @ 12582912     (1048576 each)
//  wk @ 13631488
//  wv @ 14680064
//  wo @ 15728640
//  qb @ 16777216     [B,H,S,64] bf16, pre-scaled by QSCALE
//  kb @ 20971520     [B,H,S,64] bf16
//  vt @ 25165824     [B,H,64,S] bf16 (V transposed)
//  cmask @ 29360128  (1 MB): [B][32 kblocks][S] uint64 bitmask
//  msum  @ 29884416  (128 B): [B][16 qb128] uint32, bit kb = "has masked"
#define OFF_XQ 0
#define OFF_XK 4194304
#define OFF_XV 8388608
#define OFF_WQ 12582912
#define OFF_WK 13631488
#define OFF_WV 14680064
#define OFF_WO 15728640
#define OFF_QB 16777216
#define OFF_KB 20971520
#define OFF_VT 25165824
#define OFF_CM 29360128
#define OFF_MS 29884416

__device__ __forceinline__ unsigned short f2bf(float x) {
    unsigned int u = __builtin_bit_cast(unsigned int, x);
    u += 0x7fff + ((u >> 16) & 1);            // round-to-nearest-even
    return (unsigned short)(u >> 16);
}

__device__ __forceinline__ void gl_lds16(const void* g, void* l) {
    __builtin_amdgcn_global_load_lds(
        (const __attribute__((address_space(1))) unsigned int*)g,
        (__attribute__((address_space(3))) unsigned int*)(unsigned int)(unsigned long long)l,
        16, 0, 0);
}

// ---------------------------------------------------------------------------
// fused fp32 -> bf16 convert of query/key/value + 4 weight matrices
// (also zero-inits the mask summary words for the following dispatch)
// ---------------------------------------------------------------------------
__global__ __launch_bounds__(256) void conv_all_kernel(
    const float* __restrict__ q, const float* __restrict__ k, const float* __restrict__ v,
    const float* __restrict__ wq, const float* __restrict__ wk, const float* __restrict__ wv,
    const float* __restrict__ wo, unsigned short* __restrict__ ws)
{
    if (blockIdx.x == 0 && threadIdx.x < 32)
        ((unsigned int*)(ws + OFF_MS))[threadIdx.x] = 0;
    size_t t = ((size_t)blockIdx.x * 256 + threadIdx.x) * 4;
    const float* src; unsigned short* dst; size_t off;
    if (t < 4194304)       { src = q;  dst = ws + OFF_XQ; off = t; }
    else if (t < 8388608)  { src = k;  dst = ws + OFF_XK; off = t - 4194304; }
    else if (t < 12582912) { src = v;  dst = ws + OFF_XV; off = t - 8388608; }
    else if (t < 13631488) { src = wq; dst = ws + OFF_WQ; off = t - 12582912; }
    else if (t < 14680064) { src = wk; dst = ws + OFF_WK; off = t - 13631488; }
    else if (t < 15728640) { src = wv; dst = ws + OFF_WV; off = t - 14680064; }
    else                   { src = wo; dst = ws + OFF_WO; off = t - 15728640; }
    float4 x = *(const float4*)&src[off];
    ushort4 o;
    o.x = f2bf(x.x); o.y = f2bf(x.y); o.z = f2bf(x.z); o.w = f2bf(x.w);
    *(ushort4*)&dst[off] = o;
}

// ---------------------------------------------------------------------------
// mask -> per-(b, kblock, s) 64-bit bitmask + per-(b, qb128) chunk summary
// ---------------------------------------------------------------------------
__global__ __launch_bounds__(256) void mask_compress_kernel(
    const int* __restrict__ mask, unsigned long long* __restrict__ cm,
    unsigned int* __restrict__ msum)
{
    int t = blockIdx.x * 256 + threadIdx.x;  // [0, 2*32*2048)
    int s  = t & 2047;
    int kb = (t >> 11) & 31;
    int b  = t >> 16;
    const int* mp = mask + ((size_t)b * SEQ + s) * SEQ + kb * 64;
    unsigned long long bits = 0;
    #pragma unroll
    for (int i = 0; i < 16; i++) {
        int4 m4 = *(const int4*)&mp[i * 4];
        unsigned long long nib =
            (unsigned long long)((m4.x != 0) | ((m4.y != 0) << 1) |
                                 ((m4.z != 0) << 2) | ((m4.w != 0) << 3));
        bits |= nib << (i * 4);
    }
    cm[((size_t)b * 32 + kb) * SEQ + s] = bits;
    if (bits != ~0ull)
        atomicOr(&msum[(b << 4) | (s >> 7)], 1u << kb);
}

// ---------------------------------------------------------------------------
// Shared GEMM tile body: C[128x128] += A[r0..] * W[c0..]^T, bf16 MFMA.
// A,W row-major bf16 with K stride 1024. Per-wave 64x64 = 4x4 C-frags.
// LDS rows (128 B) are XOR-ROTATED by row index: phys 16B-group p of row r
// holds logical group (p - r) & 7 (rotation folded into the GLOBAL source
// address, since global_load_lds's LDS side is fixed base + lane*16).
// Fragment reads use group ((ks*4+quad) + row) & 7 -> consecutive rows hit
// rotated bank groups (2-way aliasing = free) instead of 16 rows on one
// bank group (the 9.4e6-conflict hotspot measured in R8).
// ---------------------------------------------------------------------------
__device__ __forceinline__ void gemm_body(
    const unsigned short* A, const unsigned short* W, int r0, int c0,
    unsigned short* As, unsigned short* Bs, f32x4 acc[4][4])
{
    const int tid  = threadIdx.x;
    const int wave = tid >> 6, lane = tid & 63;
    const int quad = lane >> 4, l15 = lane & 15;
    const int wr = wave >> 1, wc = wave & 1;
    for (int k0 = 0; k0 < DMODEL; k0 += 64) {
        __syncthreads();
        #pragma unroll
        for (int r = 0; r < 4; r++) {
            int f   = r * 4096 + tid * 16;    // byte offset in 16KB tile
            int row = f >> 7;                 // tile row 0..127
            int g   = (((f >> 4) & 7) - row) & 7;   // logical group at this slot
            gl_lds16((const char*)A + (size_t)(r0 + row) * 2048 + k0 * 2 + g * 16,
                     (char*)As + r * 4096 + wave * 1024);
            gl_lds16((const char*)W + (size_t)(c0 + row) * 2048 + k0 * 2 + g * 16,
                     (char*)Bs + r * 4096 + wave * 1024);
        }
        __syncthreads();
        #pragma unroll
        for (int ks = 0; ks < 2; ks++) {
            s16x8 a[4], b[4];
            #pragma unroll
            for (int mt = 0; mt < 4; mt++) {
                int row = wr*64 + mt*16 + l15;
                a[mt] = *(const s16x8*)((const char*)As + row * 128 + ((ks*4 + quad + row) & 7) * 16);
            }
            #pragma unroll
            for (int nt = 0; nt < 4; nt++) {
                int row = wc*64 + nt*16 + l15;
                b[nt] = *(const s16x8*)((const char*)Bs + row * 128 + ((ks*4 + quad + row) & 7) * 16);
            }
            #pragma unroll
            for (int mt = 0; mt < 4; mt++)
                #pragma unroll
                for (int nt = 0; nt < 4; nt++)
                    acc[mt][nt] = __builtin_amdgcn_mfma_f32_16x16x32_bf16(a[mt], b[nt], acc[mt][nt], 0, 0, 0);
        }
    }
}

// ---------------------------------------------------------------------------
// QKV projections: z=0 -> q (scaled, [B,H,S,d]), z=1 -> k ([B,H,S,d]),
// z=2 -> V^T computed DIRECTLY as Wv * X^T (operand swap, coalesced stores).
// ---------------------------------------------------------------------------
__global__ __launch_bounds__(256) void qkv_gemm_kernel(
    unsigned short* __restrict__ ws,
    const float* __restrict__ bq, const float* __restrict__ bk, const float* __restrict__ bv)
{
    __shared__ __align__(16) unsigned short As[8192];
    __shared__ __align__(16) unsigned short Bs[8192];
    const int z = blockIdx.z;
    const unsigned short *A, *W;
    int r0, c0;
    if (z != 2) {
        A = ws + (size_t)z * 4194304;            // xq/xk
        W = ws + OFF_WQ + (size_t)z * 1048576;
        r0 = blockIdx.x * 128; c0 = blockIdx.y * 128;
    } else {
        A = ws + OFF_WV;                         // rows = output features
        W = ws + OFF_XV;                         // "cols" = seq rows
        r0 = blockIdx.y * 128; c0 = blockIdx.x * 128;
    }
    const float* bias = (z == 0) ? bq : (z == 1 ? bk : bv);
    unsigned short* outp = ws + OFF_QB + (size_t)z * 4194304;      // qb/kb/vt
    const float scale = (z == 0) ? QSCALE : 1.0f;

    f32x4 acc[4][4] = {};
    gemm_body(A, W, r0, c0, As, Bs, acc);

    const int lane = threadIdx.x & 63, wave = threadIdx.x >> 6;
    const int quad = lane >> 4, l15 = lane & 15;
    const int wr = wave >> 1, wc = wave & 1;
    if (z != 2) {
        float bias_v[4];
        #pragma unroll
        for (int nt = 0; nt < 4; nt++) bias_v[nt] = bias[c0 + wc*64 + nt*16 + l15];
        #pragma unroll
        for (int mt = 0; mt < 4; mt++) {
            #pragma unroll
            for (int nt = 0; nt < 4; nt++) {
                int c = c0 + wc*64 + nt*16 + l15;
                int hh = c >> 6, dd = c & 63;
                #pragma unroll
                for (int reg = 0; reg < 4; reg++) {
                    int r = r0 + wr*64 + mt*16 + quad*4 + reg;
                    int bb = r >> 11, ss = r & (SEQ - 1);
                    float val = (acc[mt][nt][reg] + bias_v[nt]) * scale;
                    outp[(((size_t)(bb*NHEAD + hh)) * SEQ + ss) * HDIM + dd] = f2bf(val);
                }
            }
        }
    } else {
        #pragma unroll
        for (int mt = 0; mt < 4; mt++) {
            #pragma unroll
            for (int reg = 0; reg < 4; reg++) {
                int f = r0 + wr*64 + mt*16 + quad*4 + reg;   // feature
                int hh = f >> 6, dd = f & 63;
                float bfv = bias[f];
                #pragma unroll
                for (int nt = 0; nt < 4; nt++) {
                    int r = c0 + wc*64 + nt*16 + l15;        // seq row
                    int bb = r >> 11, ss = r & (SEQ - 1);
                    outp[(((size_t)(bb*NHEAD + hh)) * HDIM + dd) * SEQ + ss] =
                        f2bf(acc[mt][nt][reg] + bfv);
                }
            }
        }
    }
}

// ---------------------------------------------------------------------------
// Out projection: out = ab @ Wo^T + bo + residual  (fp32 out)
// ---------------------------------------------------------------------------
__global__ __launch_bounds__(256) void oproj_gemm_kernel(
    const unsigned short* __restrict__ ws, const float* __restrict__ bo,
    const float* __restrict__ resid, float* __restrict__ outf)
{
    __shared__ __align__(16) unsigned short As[8192];
    __shared__ __align__(16) unsigned short Bs[8192];
    const unsigned short* A = ws + OFF_XQ;      // ab lives where xq was
    const unsigned short* W = ws + OFF_WO;
    const int r0 = blockIdx.x * 128, c0 = blockIdx.y * 128;

    f32x4 acc[4][4] = {};
    gemm_body(A, W, r0, c0, (unsigned short*)As, (unsigned short*)Bs, acc);

    const int lane = threadIdx.x & 63, wave = threadIdx.x >> 6;
    const int quad = lane >> 4, l15 = lane & 15;
    const int wr = wave >> 1, wc = wave & 1;
    #pragma unroll
    for (int mt = 0; mt < 4; mt++) {
        #pragma unroll
        for (int nt = 0; nt < 4; nt++) {
            int c = c0 + wc*64 + nt*16 + l15;
            float bv = bo[c];
            #pragma unroll
            for (int reg = 0; reg < 4; reg++) {
                int r = r0 + wr*64 + mt*16 + quad*4 + reg;
                size_t idx = (size_t)r * DMODEL + c;
                outf[idx] = acc[mt][nt][reg] + bv + resid[idx];
            }
        }
    }
}

// ---------------------------------------------------------------------------
// Flash attention, bf16 MFMA, static softmax.
// R13 = R12 structure (swapped QK^T, key-permuted K staging, P in registers,
// 0 bank conflicts) with the VALU pack path shrunk ~4x (R12 counters showed
// VALU-issue-bound: VALUBusy 63%, pack/lpart ~96 of 193 VALU cy/wave-chunk):
//   * bf16 pack via v_perm_b32 (1 op per f32 pair, byte-extract = trunc;
//     was 16 AND + 8 SHL + 8 OR)
//   * l via ones-column MFMA on the matrix pipe (2 MFMA/chunk, R5-proven;
//     was 16 lane-local VALU adds) -- sums the SAME bf16 values as P
//   * kf/vf LDS byte-offsets hoisted out of the K-loop (statically indexed
//     arrays -> stay in VGPRs; ~80 VGPR is free, occupancy grid-capped)
// ---------------------------------------------------------------------------
__global__ __launch_bounds__(512) void attn_mfma_kernel(
    const unsigned short* __restrict__ ws,
    const unsigned long long* __restrict__ cmask,
    const unsigned int* __restrict__ msum,
    unsigned short* __restrict__ ab)
{
    const int tid  = threadIdx.x;
    const int wave = tid >> 6, lane = tid & 63;
    const int quad = lane >> 4, l15 = lane & 15;
    const int h = blockIdx.y, b = blockIdx.z;
    const int qw = blockIdx.x * 128 + wave * 16;

    const char* qh = (const char*)(ws + OFF_QB + ((size_t)(b*NHEAD + h)) * SEQ * HDIM);
    const char* kh = (const char*)(ws + OFF_KB + ((size_t)(b*NHEAD + h)) * SEQ * HDIM);
    const char* vh = (const char*)(ws + OFF_VT + ((size_t)(b*NHEAD + h)) * SEQ * HDIM);

    __shared__ __align__(16) char Ks[2][8192];   // [perm key][d] rows, groups rotated
    __shared__ __align__(16) char Vs[2][8192];   // [d][key] rows, groups rotated

    const unsigned int chunkflags = msum[(b << 4) | blockIdx.x];

    // staging: 512 threads x 16B = one 8KB buffer per call; LDS row = tid>>3,
    // phys group tid&7 holds logical group ((tid&7) - row) & 7 (XOR-rotate).
    // K source row is the PERMUTED key a(row): bits [r5][r3 r2][r4][r1 r0].
    const int srow = tid >> 3;
    const int sgrp = ((tid & 7) - srow) & 7;
    const int arow = (srow & 0x23) | ((srow & 0x0C) << 1) | ((srow & 0x10) >> 2);

    #define STAGE(bf, k0)                                                       \
        do {                                                                    \
            gl_lds16(kh + (size_t)((k0) + arow) * 128 + sgrp * 16,              \
                     Ks[bf] + wave * 1024);                                     \
            gl_lds16(vh + (size_t)srow * 4096 + (size_t)(k0) * 2 + sgrp * 16,   \
                     Vs[bf] + wave * 1024);                                     \
        } while (0)

    s16x8 qa[2];
    #pragma unroll
    for (int ks = 0; ks < 2; ks++)
        qa[ks] = *(const s16x8*)(qh + (size_t)(qw + l15) * 128 + ks*64 + quad*16);

    // loop-invariant LDS fragment byte-offsets (statically indexed -> VGPRs)
    int koff[4][2], voff[4][2];
    #pragma unroll
    for (int kt = 0; kt < 4; kt++) {
        int prow = kt*16 + l15;
        koff[kt][0] = prow*128 + ((quad     + prow) & 7) * 16;
        koff[kt][1] = prow*128 + ((4 + quad + prow) & 7) * 16;
    }
    #pragma unroll
    for (int nt = 0; nt < 4; nt++) {
        int d = nt*16 + l15;
        voff[nt][0] = d*128 + ((quad     + d) & 7) * 16;
        voff[nt][1] = d*128 + ((4 + quad + d) & 7) * 16;
    }

    s16x8 onesf;
    {
        short so = (short)0x3F80;  // bf16 1.0
        if (l15 == 0) onesf = (s16x8){so, so, so, so, so, so, so, so};
        else          onesf = (s16x8){0, 0, 0, 0, 0, 0, 0, 0};
    }

    f32x4 o[4], lsum = {0.f, 0.f, 0.f, 0.f};
    #pragma unroll
    for (int nt = 0; nt < 4; nt++) o[nt] = (f32x4){0.f, 0.f, 0.f, 0.f};

    STAGE(0, 0);
    int bf = 0;
    for (int k0 = 0; k0 < SEQ; k0 += 64) {
        __syncthreads();            // vmcnt(0): buf[bf] staged, buf[bf^1] free
        // prefetch next chunk into the other buffer
        if (k0 + 64 < SEQ) STAGE(bf ^ 1, k0 + 64);

        const char* Kb = Ks[bf];
        const char* Vb = Vs[bf];
        // --- S^T = K Q^T (exp2-domain, pre-scaled), K as A-operand from the
        //     permuted LDS rows; st[kt][reg] = S[key a(kt*16+quad*4+reg)][q=l15]
        f32x4 st[4];
        #pragma unroll
        for (int kt = 0; kt < 4; kt++) {
            s16x8 kf0 = *(const s16x8*)(Kb + koff[kt][0]);
            s16x8 kf1 = *(const s16x8*)(Kb + koff[kt][1]);
            f32x4 z = {0.f, 0.f, 0.f, 0.f};
            st[kt] = __builtin_amdgcn_mfma_f32_16x16x32_bf16(kf0, qa[0], z, 0, 0, 0);
            st[kt] = __builtin_amdgcn_mfma_f32_16x16x32_bf16(kf1, qa[1], st[kt], 0, 0, 0);
        }
        // --- mask: one u64 per lane (q = qw+l15), bit = PERMUTED key index ---
        if (chunkflags & (1u << (k0 >> 6))) {
            unsigned long long cm =
                cmask[((size_t)b*32 + (k0 >> 6)) * SEQ + qw + l15];
            if (cm != ~0ull) {
                #pragma unroll
                for (int kt = 0; kt < 4; kt++)
                    #pragma unroll
                    for (int reg = 0; reg < 4; reg++) {
                        int key = (kt >> 1)*32 + quad*8 + (kt & 1)*4 + reg;
                        if (!((cm >> key) & 1)) st[kt][reg] = -1e9f;
                    }
            }
        }
        // --- P = exp2(S), packed to bf16 via v_perm_b32 (byte-extract =
        //     trunc); lane holds exactly keys ks*32+quad*8..+7 = PV A-octets.
        //     l accumulated on the matrix pipe via ones-column MFMA (same
        //     bf16 values as P -> bias cancels in P/l) ---
        #pragma unroll
        for (int ks = 0; ks < 2; ks++) {
            unsigned int pb[8];
            #pragma unroll
            for (int j = 0; j < 8; j++) {
                int kt = 2*ks + (j >> 2), r = j & 3;
                pb[j] = __builtin_bit_cast(unsigned int, exp2f(st[kt][r]));
            }
            u32x4 pw;
            pw[0] = __builtin_amdgcn_perm(pb[1], pb[0], 0x07060302u);
            pw[1] = __builtin_amdgcn_perm(pb[3], pb[2], 0x07060302u);
            pw[2] = __builtin_amdgcn_perm(pb[5], pb[4], 0x07060302u);
            pw[3] = __builtin_amdgcn_perm(pb[7], pb[6], 0x07060302u);
            s16x8 pa = __builtin_bit_cast(s16x8, pw);
            lsum = __builtin_amdgcn_mfma_f32_16x16x32_bf16(pa, onesf, lsum, 0, 0, 0);
            #pragma unroll
            for (int nt = 0; nt < 4; nt++) {
                s16x8 vf = *(const s16x8*)(Vb + voff[nt][ks]);
                o[nt] = __builtin_amdgcn_mfma_f32_16x16x32_bf16(pa, vf, o[nt], 0, 0, 0);
            }
        }
        bf ^= 1;
    }
    #undef STAGE
    // --- epilogue: O / l -> ab [B,S,DMODEL] bf16.
    //     O and lsum share the C layout: row q = quad*4+reg, col = l15
    //     (l valid at col 0 -> lane quad*16 = lane&48) ---
    #pragma unroll
    for (int reg = 0; reg < 4; reg++) {
        float lv = __shfl(lsum[reg], lane & 48);
        float inv = 1.f / lv;
        int sg = qw + quad*4 + reg;
        #pragma unroll
        for (int nt = 0; nt < 4; nt++) {
            size_t idx = ((size_t)b * SEQ + sg) * DMODEL + h*HDIM + nt*16 + l15;
            ab[idx] = f2bf(o[nt][reg] * inv);
        }
    }
}

// ---------------------------------------------------------------------------
// LayerNorm (unbiased std, (std+eps) denominator), in-place on fp32 rows
// ---------------------------------------------------------------------------
__global__ __launch_bounds__(256) void ln_kernel(
    float* __restrict__ x, const float* __restrict__ gamma,
    const float* __restrict__ beta)
{
    const int row = blockIdx.x;
    const int tid = threadIdx.x;
    float4 vals = *(const float4*)&x[(size_t)row * DMODEL + tid * 4];
    float s  = vals.x + vals.y + vals.z + vals.w;
    float ss = vals.x*vals.x + vals.y*vals.y + vals.z*vals.z + vals.w*vals.w;
    #pragma unroll
    for (int off = 32; off > 0; off >>= 1) {
        s  += __shfl_down(s, off);
        ss += __shfl_down(ss, off);
    }
    __shared__ float sbuf[4], ssbuf[4];
    __shared__ float mean_s, inv_s;
    if ((tid & 63) == 0) { sbuf[tid >> 6] = s; ssbuf[tid >> 6] = ss; }
    __syncthreads();
    if (tid == 0) {
        float S1 = 0.f, S2 = 0.f;
        #pragma unroll
        for (int i = 0; i < 4; i++) { S1 += sbuf[i]; S2 += ssbuf[i]; }
        float mean = S1 * (1.0f / DMODEL);
        float var  = (S2 - (float)DMODEL * mean * mean) * (1.0f / (DMODEL - 1));
        float sd   = sqrtf(fmaxf(var, 0.f));
        mean_s = mean;
        inv_s  = 1.f / (sd + EPS);
    }
    __syncthreads();
    float4 g  = *(const float4*)&gamma[tid * 4];
    float4 bt = *(const float4*)&beta[tid * 4];
    float4 o;
    o.x = g.x * (vals.x - mean_s) * inv_s + bt.x;
    o.y = g.y * (vals.y - mean_s) * inv_s + bt.y;
    o.z = g.z * (vals.z - mean_s) * inv_s + bt.z;
    o.w = g.w * (vals.w - mean_s) * inv_s + bt.w;
    *(float4*)&x[(size_t)row * DMODEL + tid * 4] = o;
}

extern "C" void kernel_launch(void* const* d_in, const int* in_sizes, int n_in,
                              void* d_out, int out_size, void* d_ws, size_t ws_size,
                              hipStream_t stream) {
    const float* query = (const float*)d_in[0];
    const float* key   = (const float*)d_in[1];
    const float* value = (const float*)d_in[2];
    const int*   mask  = (const int*)d_in[3];
    const float* Wq = (const float*)d_in[4];  const float* bq = (const float*)d_in[5];
    const float* Wk = (const float*)d_in[6];  const float* bk = (const float*)d_in[7];
    const float* Wv = (const float*)d_in[8];  const float* bv = (const float*)d_in[9];
    const float* Wo = (const float*)d_in[10]; const float* bo = (const float*)d_in[11];
    const float* gamma = (const float*)d_in[12];
    const float* beta  = (const float*)d_in[13];
    float* out = (float*)d_out;

    unsigned short* ws = (unsigned short*)d_ws;
    unsigned long long* cmask = (unsigned long long*)(ws + OFF_CM);
    unsigned int* msum = (unsigned int*)(ws + OFF_MS);

    conv_all_kernel<<<16384, 256, 0, stream>>>(query, key, value, Wq, Wk, Wv, Wo, ws);
    mask_compress_kernel<<<512, 256, 0, stream>>>(mask, cmask, msum);
    qkv_gemm_kernel<<<dim3(32, 8, 3), 256, 0, stream>>>(ws, bq, bk, bv);
    attn_mfma_kernel<<<dim3(SEQ/128, NHEAD, BATCH), 512, 0, stream>>>(ws, cmask, msum, ws + OFF_XQ);
    oproj_gemm_kernel<<<dim3(32, 8), 256, 0, stream>>>(ws, bo, query, out);
    ln_kernel<<<NROWS, 256, 0, stream>>>(out, gamma, beta);
}